// Round 1
// 160.950 us; speedup vs baseline: 1.0174x; 1.0174x over previous
//
#include <hip/hip_runtime.h>

// Problem constants (fixed by setup_inputs)
#define NNODES 27648
#define NEDGES 442368
#define FIN    256
#define HC     512
#define NH     4
#define CDIM   128
#define NAG    48
#define NGRP   12
#define N2     2304    // 48*48
#define NOUT   576     // 12*48
#define CAP    128     // max edges kept per output row (Poisson mean ~16)
#define EDIM   16
#define MPART  512     // meansum partial blocks

__device__ __forceinline__ float lrelu(float v, float s){ return v > 0.0f ? v : s * v; }

__device__ __forceinline__ float wsum(float v){
  #pragma unroll
  for (int off = 32; off; off >>= 1) v += __shfl_xor(v, off, 64);
  return v;
}
__device__ __forceinline__ float wmax(float v){
  #pragma unroll
  for (int off = 32; off; off >>= 1) v = fmaxf(v, __shfl_xor(v, off, 64));
  return v;
}

// K_A (fused): blocks 0..10  -> ws/wd/we precompute + zero counts
//              blocks 11..   -> edge_attr column partial sums (float4, grid-stride)
__global__ __launch_bounds__(256) void k_pre(
    const float* __restrict__ W, const float* __restrict__ att_src,
    const float* __restrict__ att_dst, const float* __restrict__ W_edge,
    const float* __restrict__ att_edge, const float* __restrict__ ea,
    float* __restrict__ ws_, float* __restrict__ wd_, float* __restrict__ we_,
    int* __restrict__ counts, float4* __restrict__ easum_part){
  int b = blockIdx.x;
  int tid = threadIdx.x;
  if (b < 11) {
    int g = b * 256 + tid;
    if (g < 1024) {
      int f = g >> 2, h = g & 3;
      const float4* wp = (const float4*)(W + f*HC + h*CDIM);
      const float4* ap = (const float4*)(att_src + h*CDIM);
      float s = 0.f;
      #pragma unroll 8
      for (int c4 = 0; c4 < CDIM/4; c4++){
        float4 wv = wp[c4], av = ap[c4];
        s += wv.x*av.x + wv.y*av.y + wv.z*av.z + wv.w*av.w;
      }
      ws_[g] = s;
    } else if (g < 2048) {
      int gg = g - 1024; int f = gg >> 2, h = gg & 3;
      const float4* wp = (const float4*)(W + f*HC + h*CDIM);
      const float4* ap = (const float4*)(att_dst + h*CDIM);
      float s = 0.f;
      #pragma unroll 8
      for (int c4 = 0; c4 < CDIM/4; c4++){
        float4 wv = wp[c4], av = ap[c4];
        s += wv.x*av.x + wv.y*av.y + wv.z*av.z + wv.w*av.w;
      }
      wd_[gg] = s;
    } else if (g < 2112) {
      int gg = g - 2048; int d = gg >> 2, h = gg & 3;
      const float4* wp = (const float4*)(W_edge + d*HC + h*CDIM);
      const float4* ap = (const float4*)(att_edge + h*CDIM);
      float s = 0.f;
      #pragma unroll 8
      for (int c4 = 0; c4 < CDIM/4; c4++){
        float4 wv = wp[c4], av = ap[c4];
        s += wv.x*av.x + wv.y*av.y + wv.z*av.z + wv.w*av.w;
      }
      we_[gg] = s;
    } else if (g < 2112 + NOUT) {
      counts[g - 2112] = 0;
    }
  } else {
    // edge_attr partial column sums; col-group = idx & 3 (invariant under stride)
    int pb = b - 11;
    const float4* p = (const float4*)ea;
    const int total = NEDGES * 4;           // float4 count
    float4 acc = make_float4(0.f, 0.f, 0.f, 0.f);
    for (int i = pb*256 + tid; i < total; i += MPART*256){
      float4 v = p[i];
      acc.x += v.x; acc.y += v.y; acc.z += v.z; acc.w += v.w;
    }
    // reduce across the 16 lanes sharing lane&3
    #pragma unroll
    for (int off = 4; off <= 32; off <<= 1){
      acc.x += __shfl_xor(acc.x, off, 64);
      acc.y += __shfl_xor(acc.y, off, 64);
      acc.z += __shfl_xor(acc.z, off, 64);
      acc.w += __shfl_xor(acc.w, off, 64);
    }
    __shared__ float4 sd4[16];
    int lane = tid & 63, wave = tid >> 6;
    if (lane < 4) sd4[wave*4 + lane] = acc;
    __syncthreads();
    if (tid < 4){
      float4 t = sd4[tid];
      float4 a = sd4[4+tid], c = sd4[8+tid], d = sd4[12+tid];
      t.x += a.x + c.x + d.x; t.y += a.y + c.y + d.y;
      t.z += a.z + c.z + d.z; t.w += a.w + c.w + d.w;
      easum_part[pb*4 + tid] = t;
    }
  }
}

// K_B: blocks 0..1727 bin edges whose dst is diagonal; block 1728 reduces easum.
__global__ __launch_bounds__(256) void k_scan(const int* __restrict__ ei,
    const float* __restrict__ ea, const float* __restrict__ we_,
    int* __restrict__ counts, int* __restrict__ slist, float* __restrict__ aed,
    const float* __restrict__ easum_part, float* __restrict__ easum){
  int tid = threadIdx.x;
  if (blockIdx.x == NEDGES/256){
    // reduce 512 partial blocks x 16 cols -> easum[16]
    int col = tid & 15, part = tid >> 4;          // 16 parts x 32 pblocks
    float s = 0.f;
    for (int pb = 0; pb < MPART/16; pb++)
      s += easum_part[(part*(MPART/16) + pb)*16 + col];
    __shared__ float sd[256];
    sd[tid] = s;
    __syncthreads();
    if (tid < 16){
      float t = 0.f;
      #pragma unroll
      for (int i = 0; i < 16; i++) t += sd[i*16 + tid];
      easum[tid] = t;
    }
    return;
  }
  int e = blockIdx.x*256 + tid;
  int dst = ei[NEDGES + e];
  int r = dst % N2;
  if (r % 49) return;
  int row = (dst / N2) * NAG + r / 49;
  int pos = atomicAdd(&counts[row], 1);
  if (pos >= CAP) return;
  slist[row*CAP + pos] = ei[e];
  const float* eap = ea + (size_t)e*EDIM;
  float a0=0.f,a1=0.f,a2=0.f,a3=0.f;
  #pragma unroll
  for (int d = 0; d < EDIM; d++){
    float v = eap[d];
    a0 += v*we_[d*4+0]; a1 += v*we_[d*4+1]; a2 += v*we_[d*4+2]; a3 += v*we_[d*4+3];
  }
  float* ap = aed + (size_t)(row*CAP+pos)*4;
  ap[0]=a0; ap[1]=a1; ap[2]=a2; ap[3]=a3;
}

// K_C (mega): per output row: logits -> segment softmax -> z (LDS)
//             -> h2 = lrelu(z@W + bias) (LDS) -> out = lrelu(h2@fcW + fcb)
// z and h2 never touch global memory; the two downstream gemms now run at
// 576-block parallelism instead of 288/144.
__global__ __launch_bounds__(256) void k_mega(const float* __restrict__ x,
    const float* __restrict__ ws_, const float* __restrict__ wd_,
    const float* __restrict__ we_, const float* __restrict__ easum,
    const int* __restrict__ counts, const int* __restrict__ slist,
    const float* __restrict__ aed,
    const float* __restrict__ W, const float* __restrict__ bias,
    const float* __restrict__ fcW, const float* __restrict__ fcb,
    float* __restrict__ out){
  __shared__ float lg[(CAP+1)*4];
  __shared__ int   srcs[CAP];
  __shared__ float adst_s[4];
  __shared__ float zs[4*256];      // 16 KB: attention-weighted x sums per head
  __shared__ float hs[512];        //  2 KB: gat output row (post-lrelu)
  int row = blockIdx.x;
  int g = row / NAG, j = row - g*NAG;
  int dst = g*N2 + j*49;
  int tid = threadIdx.x;
  int lane = tid & 63, wave = tid >> 6;
  int k = counts[row]; if (k > CAP) k = CAP;

  // per-lane slice of ws (f = lane*4+q, all 4 heads)
  float wsr[4][4];
  #pragma unroll
  for (int q = 0; q < 4; q++){
    float4 t = *(const float4*)(ws_ + (lane*4+q)*4);
    wsr[q][0]=t.x; wsr[q][1]=t.y; wsr[q][2]=t.z; wsr[q][3]=t.w;
  }

  // edges round-robin over 4 waves
  for (int i = wave; i < k; i += 4){
    int src = slist[row*CAP + i];
    float4 aedv = *(const float4*)(aed + (size_t)(row*CAP+i)*4);
    float4 xv = *(const float4*)(x + (size_t)src*FIN + lane*4);
    float p0 = xv.x*wsr[0][0] + xv.y*wsr[1][0] + xv.z*wsr[2][0] + xv.w*wsr[3][0];
    float p1 = xv.x*wsr[0][1] + xv.y*wsr[1][1] + xv.z*wsr[2][1] + xv.w*wsr[3][1];
    float p2 = xv.x*wsr[0][2] + xv.y*wsr[1][2] + xv.z*wsr[2][2] + xv.w*wsr[3][2];
    float p3 = xv.x*wsr[0][3] + xv.y*wsr[1][3] + xv.z*wsr[2][3] + xv.w*wsr[3][3];
    p0 = wsum(p0); p1 = wsum(p1); p2 = wsum(p2); p3 = wsum(p3);
    if (lane == 0){
      srcs[i] = src;
      lg[i*4+0] = p0 + aedv.x; lg[i*4+1] = p1 + aedv.y;
      lg[i*4+2] = p2 + aedv.z; lg[i*4+3] = p3 + aedv.w;
    }
  }

  // wave 0: a_dst, self-loop logit (a_src(dst) + mean_ea@we)
  if (wave == 0){
    float wdr[4][4];
    #pragma unroll
    for (int q = 0; q < 4; q++){
      float4 t = *(const float4*)(wd_ + (lane*4+q)*4);
      wdr[q][0]=t.x; wdr[q][1]=t.y; wdr[q][2]=t.z; wdr[q][3]=t.w;
    }
    float4 xv = *(const float4*)(x + (size_t)dst*FIN + lane*4);
    float pd[4], ps[4];
    #pragma unroll
    for (int h = 0; h < 4; h++){
      pd[h] = xv.x*wdr[0][h] + xv.y*wdr[1][h] + xv.z*wdr[2][h] + xv.w*wdr[3][h];
      ps[h] = xv.x*wsr[0][h] + xv.y*wsr[1][h] + xv.z*wsr[2][h] + xv.w*wsr[3][h];
    }
    const float invE = 1.0f/(float)NEDGES;
    float md = (lane < 16) ? easum[lane]*invE : 0.f;
    float al[4];
    #pragma unroll
    for (int h = 0; h < 4; h++){
      float c = (lane < 16) ? md*we_[lane*4+h] : 0.f;
      al[h] = wsum(c);
      pd[h] = wsum(pd[h]);
      ps[h] = wsum(ps[h]);
    }
    if (lane == 0){
      #pragma unroll
      for (int h = 0; h < 4; h++){
        adst_s[h] = pd[h];
        lg[k*4+h] = ps[h] + al[h];
      }
    }
  }
  __syncthreads();

  // segment softmax: wave w handles head w over k+1 entries
  {
    int h = wave;
    float ad = adst_s[h];
    float m = -1e30f;
    for (int i = lane; i <= k; i += 64){
      float v = lrelu(lg[i*4+h] + ad, 0.2f);
      lg[i*4+h] = v;
      m = fmaxf(m, v);
    }
    m = wmax(m);
    float s = 0.f;
    for (int i = lane; i <= k; i += 64){
      float e = __expf(lg[i*4+h] - m);
      lg[i*4+h] = e;
      s += e;
    }
    s = wsum(s);
    float inv = 1.0f/(s + 1e-16f);
    for (int i = lane; i <= k; i += 64) lg[i*4+h] *= inv;
  }
  __syncthreads();

  // z accumulation into LDS: thread = feature f
  {
    int f = tid;
    float a0=0.f,a1=0.f,a2=0.f,a3=0.f;
    for (int i = 0; i < k; i++){
      float xv = x[(size_t)srcs[i]*FIN + f];
      a0 += lg[i*4+0]*xv; a1 += lg[i*4+1]*xv; a2 += lg[i*4+2]*xv; a3 += lg[i*4+3]*xv;
    }
    {
      float xv = x[(size_t)dst*FIN + f];
      a0 += lg[k*4+0]*xv; a1 += lg[k*4+1]*xv; a2 += lg[k*4+2]*xv; a3 += lg[k*4+3]*xv;
    }
    zs[0*256+f]=a0; zs[1*256+f]=a1; zs[2*256+f]=a2; zs[3*256+f]=a3;
  }
  __syncthreads();

  // gemm1: h2[o] = lrelu( z[head(o),:] @ W[:,o] + bias[o] ), o = tid and tid+256
  // head(o1) = tid>>7 (0/1), head(o2) = 2 + (tid>>7); per-wave uniform -> LDS broadcast
  {
    int o1 = tid, o2 = tid + 256;
    const float* z1 = zs + ((tid >> 7) << 8);        // head 0 or 1
    const float* z2 = zs + 512 + ((tid >> 7) << 8);  // head 2 or 3
    const float* W1 = W + o1;
    float acc1 = 0.f, acc2 = 0.f;
    for (int ff = 0; ff < 256; ff += 8){
      #pragma unroll
      for (int u = 0; u < 8; u++){
        float w1 = W1[(size_t)(ff+u)*HC];
        float w2 = W1[(size_t)(ff+u)*HC + 256];
        acc1 += z1[ff+u]*w1;
        acc2 += z2[ff+u]*w2;
      }
    }
    hs[o1] = lrelu(acc1 + bias[o1], 0.01f);
    hs[o2] = lrelu(acc2 + bias[o2], 0.01f);
  }
  __syncthreads();

  // gemm2: out[row, j] = lrelu( hs @ fcW[:,j] + fcb[j] ), j = tid
  {
    const float* Fw = fcW + tid;
    float acc = 0.f;
    for (int k0 = 0; k0 < 512; k0 += 8){
      #pragma unroll
      for (int u = 0; u < 8; u++)
        acc += hs[k0+u] * Fw[(size_t)(k0+u)*256];
    }
    out[(size_t)row*256 + tid] = lrelu(acc + fcb[tid], 0.01f);
  }
}

extern "C" void kernel_launch(void* const* d_in, const int* in_sizes, int n_in,
                              void* d_out, int out_size, void* d_ws, size_t ws_size,
                              hipStream_t stream) {
  const float* x        = (const float*)d_in[0];
  const int*   ei       = (const int*)  d_in[1];
  const float* ea       = (const float*)d_in[2];
  // d_in[3]=num_groups, d_in[4]=agents_per_group (fixed: 12, 48)
  const float* W        = (const float*)d_in[5];
  const float* att_src  = (const float*)d_in[6];
  const float* att_dst  = (const float*)d_in[7];
  const float* W_edge   = (const float*)d_in[8];
  const float* att_edge = (const float*)d_in[9];
  const float* bias     = (const float*)d_in[10];
  const float* fcW      = (const float*)d_in[11];
  const float* fcb      = (const float*)d_in[12];
  float* out = (float*)d_out;

  float* w = (float*)d_ws;
  float*  ws_       = w;                    // 1024
  float*  wd_       = w + 1024;             // 1024
  float*  we_       = w + 2048;             // 64
  float*  easum     = w + 2112;             // 16
  int*    counts    = (int*)(w + 2128);     // 576
  float*  easum_p   = w + 2704;             // 512*16 = 8192 (16B-aligned)
  int*    slist     = (int*)(w + 10896);    // 576*128 = 73728
  float*  aed       = w + 84624;            // 576*128*4 = 294912 (16B-aligned)

  k_pre<<<11 + MPART, 256, 0, stream>>>(W, att_src, att_dst, W_edge, att_edge, ea,
                                        ws_, wd_, we_, counts, (float4*)easum_p);
  k_scan<<<NEDGES/256 + 1, 256, 0, stream>>>(ei, ea, we_, counts, slist, aed,
                                             easum_p, easum);
  k_mega<<<NOUT, 256, 0, stream>>>(x, ws_, wd_, we_, easum, counts, slist, aed,
                                   W, bias, fcW, fcb, out);
}

// Round 4
// 156.564 us; speedup vs baseline: 1.0459x; 1.0280x over previous
//
#include <hip/hip_runtime.h>

// Problem constants (fixed by setup_inputs)
#define NNODES 27648
#define NEDGES 442368
#define FIN    256
#define HC     512
#define NH     4
#define CDIM   128
#define NAG    48
#define NGRP   12
#define N2     2304    // 48*48
#define NOUT   576     // 12*48
#define CAP    128     // max edges kept per output row (Poisson mean ~16)
#define EDIM   16
#define MPART  512     // meansum partial blocks

// R3: resubmit of the R1 experiment (R2/R3 container-acquisition failures,
// kernel never executed). LDS bulk buffers now declared float4 for
// guaranteed 16B alignment of b128 LDS ops.

__device__ __forceinline__ float lrelu(float v, float s){ return v > 0.0f ? v : s * v; }

__device__ __forceinline__ float wsum(float v){
  #pragma unroll
  for (int off = 32; off; off >>= 1) v += __shfl_xor(v, off, 64);
  return v;
}
__device__ __forceinline__ float wmax(float v){
  #pragma unroll
  for (int off = 32; off; off >>= 1) v = fmaxf(v, __shfl_xor(v, off, 64));
  return v;
}

// K_A (fused): blocks 0..10  -> ws/wd/we precompute + zero counts
//              blocks 11..   -> edge_attr column partial sums (float4, grid-stride)
__global__ __launch_bounds__(256) void k_pre(
    const float* __restrict__ W, const float* __restrict__ att_src,
    const float* __restrict__ att_dst, const float* __restrict__ W_edge,
    const float* __restrict__ att_edge, const float* __restrict__ ea,
    float* __restrict__ ws_, float* __restrict__ wd_, float* __restrict__ we_,
    int* __restrict__ counts, float4* __restrict__ easum_part){
  int b = blockIdx.x;
  int tid = threadIdx.x;
  if (b < 11) {
    int g = b * 256 + tid;
    if (g < 1024) {
      int f = g >> 2, h = g & 3;
      const float4* wp = (const float4*)(W + f*HC + h*CDIM);
      const float4* ap = (const float4*)(att_src + h*CDIM);
      float s = 0.f;
      #pragma unroll 8
      for (int c4 = 0; c4 < CDIM/4; c4++){
        float4 wv = wp[c4], av = ap[c4];
        s += wv.x*av.x + wv.y*av.y + wv.z*av.z + wv.w*av.w;
      }
      ws_[g] = s;
    } else if (g < 2048) {
      int gg = g - 1024; int f = gg >> 2, h = gg & 3;
      const float4* wp = (const float4*)(W + f*HC + h*CDIM);
      const float4* ap = (const float4*)(att_dst + h*CDIM);
      float s = 0.f;
      #pragma unroll 8
      for (int c4 = 0; c4 < CDIM/4; c4++){
        float4 wv = wp[c4], av = ap[c4];
        s += wv.x*av.x + wv.y*av.y + wv.z*av.z + wv.w*av.w;
      }
      wd_[gg] = s;
    } else if (g < 2112) {
      int gg = g - 2048; int d = gg >> 2, h = gg & 3;
      const float4* wp = (const float4*)(W_edge + d*HC + h*CDIM);
      const float4* ap = (const float4*)(att_edge + h*CDIM);
      float s = 0.f;
      #pragma unroll 8
      for (int c4 = 0; c4 < CDIM/4; c4++){
        float4 wv = wp[c4], av = ap[c4];
        s += wv.x*av.x + wv.y*av.y + wv.z*av.z + wv.w*av.w;
      }
      we_[gg] = s;
    } else if (g < 2112 + NOUT) {
      counts[g - 2112] = 0;
    }
  } else {
    // edge_attr partial column sums; col-group = idx & 3 (invariant under stride)
    int pb = b - 11;
    const float4* p = (const float4*)ea;
    const int total = NEDGES * 4;           // float4 count
    float4 acc = make_float4(0.f, 0.f, 0.f, 0.f);
    for (int i = pb*256 + tid; i < total; i += MPART*256){
      float4 v = p[i];
      acc.x += v.x; acc.y += v.y; acc.z += v.z; acc.w += v.w;
    }
    // reduce across the 16 lanes sharing lane&3
    #pragma unroll
    for (int off = 4; off <= 32; off <<= 1){
      acc.x += __shfl_xor(acc.x, off, 64);
      acc.y += __shfl_xor(acc.y, off, 64);
      acc.z += __shfl_xor(acc.z, off, 64);
      acc.w += __shfl_xor(acc.w, off, 64);
    }
    __shared__ float4 sd4[16];
    int lane = tid & 63, wave = tid >> 6;
    if (lane < 4) sd4[wave*4 + lane] = acc;
    __syncthreads();
    if (tid < 4){
      float4 t = sd4[tid];
      float4 a = sd4[4+tid], c = sd4[8+tid], d = sd4[12+tid];
      t.x += a.x + c.x + d.x; t.y += a.y + c.y + d.y;
      t.z += a.z + c.z + d.z; t.w += a.w + c.w + d.w;
      easum_part[pb*4 + tid] = t;
    }
  }
}

// K_B: blocks 0..1727 bin edges whose dst is diagonal; block 1728 reduces easum.
__global__ __launch_bounds__(256) void k_scan(const int* __restrict__ ei,
    const float* __restrict__ ea, const float* __restrict__ we_,
    int* __restrict__ counts, int* __restrict__ slist, float* __restrict__ aed,
    const float* __restrict__ easum_part, float* __restrict__ easum){
  int tid = threadIdx.x;
  if (blockIdx.x == NEDGES/256){
    // reduce 512 partial blocks x 16 cols -> easum[16]
    int col = tid & 15, part = tid >> 4;          // 16 parts x 32 pblocks
    float s = 0.f;
    for (int pb = 0; pb < MPART/16; pb++)
      s += easum_part[(part*(MPART/16) + pb)*16 + col];
    __shared__ float sd[256];
    sd[tid] = s;
    __syncthreads();
    if (tid < 16){
      float t = 0.f;
      #pragma unroll
      for (int i = 0; i < 16; i++) t += sd[i*16 + tid];
      easum[tid] = t;
    }
    return;
  }
  int e = blockIdx.x*256 + tid;
  int dst = ei[NEDGES + e];
  int r = dst % N2;
  if (r % 49) return;
  int row = (dst / N2) * NAG + r / 49;
  int pos = atomicAdd(&counts[row], 1);
  if (pos >= CAP) return;
  slist[row*CAP + pos] = ei[e];
  const float* eap = ea + (size_t)e*EDIM;
  float a0=0.f,a1=0.f,a2=0.f,a3=0.f;
  #pragma unroll
  for (int d = 0; d < EDIM; d++){
    float v = eap[d];
    a0 += v*we_[d*4+0]; a1 += v*we_[d*4+1]; a2 += v*we_[d*4+2]; a3 += v*we_[d*4+3];
  }
  float* ap = aed + (size_t)(row*CAP+pos)*4;
  ap[0]=a0; ap[1]=a1; ap[2]=a2; ap[3]=a3;
}

// K_C (mega): per output row: logits -> segment softmax -> z (LDS, float4 path)
//             -> h2 = lrelu(z@W + bias) (LDS) -> out = lrelu(h2@fcW + fcb)
// All inner loops use dwordx4 loads with reduction splits to maximize
// memory-level parallelism at the grid's low (2.25 blocks/CU) occupancy.
__global__ __launch_bounds__(256) void k_mega(const float* __restrict__ x,
    const float* __restrict__ ws_, const float* __restrict__ wd_,
    const float* __restrict__ we_, const float* __restrict__ easum,
    const int* __restrict__ counts, const int* __restrict__ slist,
    const float* __restrict__ aed,
    const float* __restrict__ W, const float* __restrict__ bias,
    const float* __restrict__ fcW, const float* __restrict__ fcb,
    float* __restrict__ out){
  __shared__ float  lg[(CAP+1)*4];
  __shared__ int    srcs[CAP+1];
  __shared__ float  adst_s[4];
  __shared__ float4 pz4[4*256];    // 16 KB: per-wave z partials [wave][h*64+lane]
  __shared__ float4 zs4[256];      //  4 KB: combined z (viewed as [h*256+f] floats)
  __shared__ float4 ph4[256];      //  4 KB: gemm1 partials [half][128]
  __shared__ float  hs[512];       //  2 KB: gat output row (post-lrelu)
  __shared__ float4 pq4[256];      //  4 KB: gemm2 partials [quarter][64]
  int row = blockIdx.x;
  int g = row / NAG, j = row - g*NAG;
  int dst = g*N2 + j*49;
  int tid = threadIdx.x;
  int lane = tid & 63, wave = tid >> 6;
  int k = counts[row]; if (k > CAP) k = CAP;

  // per-lane slice of ws (f = lane*4+q, all 4 heads)
  float wsr[4][4];
  #pragma unroll
  for (int q = 0; q < 4; q++){
    float4 t = *(const float4*)(ws_ + (lane*4+q)*4);
    wsr[q][0]=t.x; wsr[q][1]=t.y; wsr[q][2]=t.z; wsr[q][3]=t.w;
  }

  // edges round-robin over 4 waves
  for (int i = wave; i < k; i += 4){
    int src = slist[row*CAP + i];
    float4 aedv = *(const float4*)(aed + (size_t)(row*CAP+i)*4);
    float4 xv = *(const float4*)(x + (size_t)src*FIN + lane*4);
    float p0 = xv.x*wsr[0][0] + xv.y*wsr[1][0] + xv.z*wsr[2][0] + xv.w*wsr[3][0];
    float p1 = xv.x*wsr[0][1] + xv.y*wsr[1][1] + xv.z*wsr[2][1] + xv.w*wsr[3][1];
    float p2 = xv.x*wsr[0][2] + xv.y*wsr[1][2] + xv.z*wsr[2][2] + xv.w*wsr[3][2];
    float p3 = xv.x*wsr[0][3] + xv.y*wsr[1][3] + xv.z*wsr[2][3] + xv.w*wsr[3][3];
    p0 = wsum(p0); p1 = wsum(p1); p2 = wsum(p2); p3 = wsum(p3);
    if (lane == 0){
      srcs[i] = src;
      lg[i*4+0] = p0 + aedv.x; lg[i*4+1] = p1 + aedv.y;
      lg[i*4+2] = p2 + aedv.z; lg[i*4+3] = p3 + aedv.w;
    }
  }

  // wave 0: a_dst, self-loop logit (a_src(dst) + mean_ea@we)
  if (wave == 0){
    float wdr[4][4];
    #pragma unroll
    for (int q = 0; q < 4; q++){
      float4 t = *(const float4*)(wd_ + (lane*4+q)*4);
      wdr[q][0]=t.x; wdr[q][1]=t.y; wdr[q][2]=t.z; wdr[q][3]=t.w;
    }
    float4 xv = *(const float4*)(x + (size_t)dst*FIN + lane*4);
    float pd[4], ps[4];
    #pragma unroll
    for (int h = 0; h < 4; h++){
      pd[h] = xv.x*wdr[0][h] + xv.y*wdr[1][h] + xv.z*wdr[2][h] + xv.w*wdr[3][h];
      ps[h] = xv.x*wsr[0][h] + xv.y*wsr[1][h] + xv.z*wsr[2][h] + xv.w*wsr[3][h];
    }
    const float invE = 1.0f/(float)NEDGES;
    float md = (lane < 16) ? easum[lane]*invE : 0.f;
    float al[4];
    #pragma unroll
    for (int h = 0; h < 4; h++){
      float c = (lane < 16) ? md*we_[lane*4+h] : 0.f;
      al[h] = wsum(c);
      pd[h] = wsum(pd[h]);
      ps[h] = wsum(ps[h]);
    }
    if (lane == 0){
      #pragma unroll
      for (int h = 0; h < 4; h++){
        adst_s[h] = pd[h];
        lg[k*4+h] = ps[h] + al[h];
      }
      srcs[k] = dst;   // self-loop src for unified z-accumulation
    }
  }
  __syncthreads();

  // segment softmax: wave w handles head w over k+1 entries
  {
    int h = wave;
    float ad = adst_s[h];
    float m = -1e30f;
    for (int i = lane; i <= k; i += 64){
      float v = lrelu(lg[i*4+h] + ad, 0.2f);
      lg[i*4+h] = v;
      m = fmaxf(m, v);
    }
    m = wmax(m);
    float s = 0.f;
    for (int i = lane; i <= k; i += 64){
      float e = __expf(lg[i*4+h] - m);
      lg[i*4+h] = e;
      s += e;
    }
    s = wsum(s);
    float inv = 1.0f/(s + 1e-16f);
    for (int i = lane; i <= k; i += 64) lg[i*4+h] *= inv;
  }
  __syncthreads();

  // z accumulation: wave w handles edges i = w, w+4, ... (incl self at i=k).
  // lane holds features 4*lane..4*lane+3 for all 4 heads (float4 x loads).
  {
    float acc[4][4];
    #pragma unroll
    for (int h = 0; h < 4; h++)
      #pragma unroll
      for (int c = 0; c < 4; c++) acc[h][c] = 0.f;
    for (int i = wave; i <= k; i += 4){
      int src = srcs[i];
      float4 xv = *(const float4*)(x + (size_t)src*FIN + lane*4);
      float a0 = lg[i*4+0], a1 = lg[i*4+1], a2 = lg[i*4+2], a3 = lg[i*4+3];
      acc[0][0] += a0*xv.x; acc[0][1] += a0*xv.y; acc[0][2] += a0*xv.z; acc[0][3] += a0*xv.w;
      acc[1][0] += a1*xv.x; acc[1][1] += a1*xv.y; acc[1][2] += a1*xv.z; acc[1][3] += a1*xv.w;
      acc[2][0] += a2*xv.x; acc[2][1] += a2*xv.y; acc[2][2] += a2*xv.z; acc[2][3] += a2*xv.w;
      acc[3][0] += a3*xv.x; acc[3][1] += a3*xv.y; acc[3][2] += a3*xv.z; acc[3][3] += a3*xv.w;
    }
    #pragma unroll
    for (int h = 0; h < 4; h++)
      pz4[wave*256 + h*64 + lane] =
        make_float4(acc[h][0], acc[h][1], acc[h][2], acc[h][3]);
  }
  __syncthreads();
  {
    // combine 4 wave-partials -> zs
    float4 a = pz4[0*256+tid], b = pz4[1*256+tid],
           c = pz4[2*256+tid], d = pz4[3*256+tid];
    zs4[tid] = make_float4(a.x+b.x+c.x+d.x, a.y+b.y+c.y+d.y,
                           a.z+b.z+c.z+d.z, a.w+b.w+c.w+d.w);
  }
  __syncthreads();

  // gemm1: thread = (col-group cg: cols 4cg..4cg+3, reduction half).
  // float4 weight loads (1 KB/wave/instr), partial-combine via LDS.
  {
    int cg = tid & 127;
    int half = tid >> 7;
    int h = cg >> 5;                       // head of this col group
    const float* zp = (const float*)zs4 + h*256 + half*128;
    const float4* Wp = (const float4*)(W + (size_t)half*128*HC) + cg;
    float4 acc = make_float4(0.f,0.f,0.f,0.f);
    #pragma unroll 8
    for (int r = 0; r < 128; r++){
      float4 w4 = Wp[(size_t)r*(HC/4)];
      float zv = zp[r];
      acc.x += zv*w4.x; acc.y += zv*w4.y; acc.z += zv*w4.z; acc.w += zv*w4.w;
    }
    ph4[half*128 + cg] = acc;
  }
  __syncthreads();
  if (tid < 128){
    float4 a = ph4[tid], b = ph4[128+tid];
    float4 bs = *(const float4*)(bias + 4*tid);
    hs[4*tid+0] = lrelu(a.x+b.x+bs.x, 0.01f);
    hs[4*tid+1] = lrelu(a.y+b.y+bs.y, 0.01f);
    hs[4*tid+2] = lrelu(a.z+b.z+bs.z, 0.01f);
    hs[4*tid+3] = lrelu(a.w+b.w+bs.w, 0.01f);
  }
  __syncthreads();

  // gemm2: thread = (col-group cg: cols 4cg..4cg+3, reduction quarter q)
  {
    int cg = tid & 63;
    int q  = tid >> 6;
    const float4* Fp = (const float4*)(fcW + (size_t)q*128*256) + cg;
    const float* hp = hs + q*128;
    float4 acc = make_float4(0.f,0.f,0.f,0.f);
    #pragma unroll 8
    for (int r = 0; r < 128; r++){
      float4 w4 = Fp[(size_t)r*64];
      float hv = hp[r];
      acc.x += hv*w4.x; acc.y += hv*w4.y; acc.z += hv*w4.z; acc.w += hv*w4.w;
    }
    pq4[q*64 + cg] = acc;
  }
  __syncthreads();
  if (tid < 64){
    float4 a = pq4[tid],      b = pq4[64+tid];
    float4 c = pq4[128+tid],  d = pq4[192+tid];
    float4 bs = *(const float4*)(fcb + 4*tid);
    float4 o;
    o.x = lrelu(a.x+b.x+c.x+d.x+bs.x, 0.01f);
    o.y = lrelu(a.y+b.y+c.y+d.y+bs.y, 0.01f);
    o.z = lrelu(a.z+b.z+c.z+d.z+bs.z, 0.01f);
    o.w = lrelu(a.w+b.w+c.w+d.w+bs.w, 0.01f);
    *(float4*)(out + (size_t)row*256 + 4*tid) = o;
  }
}

extern "C" void kernel_launch(void* const* d_in, const int* in_sizes, int n_in,
                              void* d_out, int out_size, void* d_ws, size_t ws_size,
                              hipStream_t stream) {
  const float* x        = (const float*)d_in[0];
  const int*   ei       = (const int*)  d_in[1];
  const float* ea       = (const float*)d_in[2];
  // d_in[3]=num_groups, d_in[4]=agents_per_group (fixed: 12, 48)
  const float* W        = (const float*)d_in[5];
  const float* att_src  = (const float*)d_in[6];
  const float* att_dst  = (const float*)d_in[7];
  const float* W_edge   = (const float*)d_in[8];
  const float* att_edge = (const float*)d_in[9];
  const float* bias     = (const float*)d_in[10];
  const float* fcW      = (const float*)d_in[11];
  const float* fcb      = (const float*)d_in[12];
  float* out = (float*)d_out;

  float* w = (float*)d_ws;
  float*  ws_       = w;                    // 1024
  float*  wd_       = w + 1024;             // 1024
  float*  we_       = w + 2048;             // 64
  float*  easum     = w + 2112;             // 16
  int*    counts    = (int*)(w + 2128);     // 576
  float*  easum_p   = w + 2704;             // 512*16 = 8192 (16B-aligned)
  int*    slist     = (int*)(w + 10896);    // 576*128 = 73728
  float*  aed       = w + 84624;            // 576*128*4 = 294912 (16B-aligned)

  k_pre<<<11 + MPART, 256, 0, stream>>>(W, att_src, att_dst, W_edge, att_edge, ea,
                                        ws_, wd_, we_, counts, (float4*)easum_p);
  k_scan<<<NEDGES/256 + 1, 256, 0, stream>>>(ei, ea, we_, counts, slist, aed,
                                             easum_p, easum);
  k_mega<<<NOUT, 256, 0, stream>>>(x, ws_, wd_, we_, easum, counts, slist, aed,
                                   W, bias, fcW, fcb, out);
}

// Round 5
// 149.566 us; speedup vs baseline: 1.0949x; 1.0468x over previous
//
#include <hip/hip_runtime.h>

// Problem constants (fixed by setup_inputs)
#define NNODES 27648
#define NEDGES 442368
#define FIN    256
#define HC     512
#define NH     4
#define CDIM   128
#define NAG    48
#define NGRP   12
#define N2     2304    // 48*48
#define NOUT   576     // 12*48
#define CAP    128     // max edges kept per output row (Poisson mean ~16)
#define EDIM   16
#define MPART  512     // meansum partial blocks

// R5: k_mega now processes 2 rows per block (288 blocks x 512 threads).
// Each W/fcW float4 load feeds both rows -> aggregate weight L2 traffic
// halves (576->288 MB); reduction split 4/8-way across 8 waves. Attention
// runs the two rows on wave halves. Scratch LDS is phase-aliased (49 KB).

__device__ __forceinline__ float lrelu(float v, float s){ return v > 0.0f ? v : s * v; }

__device__ __forceinline__ float wsum(float v){
  #pragma unroll
  for (int off = 32; off; off >>= 1) v += __shfl_xor(v, off, 64);
  return v;
}
__device__ __forceinline__ float wmax(float v){
  #pragma unroll
  for (int off = 32; off; off >>= 1) v = fmaxf(v, __shfl_xor(v, off, 64));
  return v;
}

// K_A (fused): blocks 0..10  -> ws/wd/we precompute + zero counts
//              blocks 11..   -> edge_attr column partial sums (float4, grid-stride)
__global__ __launch_bounds__(256) void k_pre(
    const float* __restrict__ W, const float* __restrict__ att_src,
    const float* __restrict__ att_dst, const float* __restrict__ W_edge,
    const float* __restrict__ att_edge, const float* __restrict__ ea,
    float* __restrict__ ws_, float* __restrict__ wd_, float* __restrict__ we_,
    int* __restrict__ counts, float4* __restrict__ easum_part){
  int b = blockIdx.x;
  int tid = threadIdx.x;
  if (b < 11) {
    int g = b * 256 + tid;
    if (g < 1024) {
      int f = g >> 2, h = g & 3;
      const float4* wp = (const float4*)(W + f*HC + h*CDIM);
      const float4* ap = (const float4*)(att_src + h*CDIM);
      float s = 0.f;
      #pragma unroll 8
      for (int c4 = 0; c4 < CDIM/4; c4++){
        float4 wv = wp[c4], av = ap[c4];
        s += wv.x*av.x + wv.y*av.y + wv.z*av.z + wv.w*av.w;
      }
      ws_[g] = s;
    } else if (g < 2048) {
      int gg = g - 1024; int f = gg >> 2, h = gg & 3;
      const float4* wp = (const float4*)(W + f*HC + h*CDIM);
      const float4* ap = (const float4*)(att_dst + h*CDIM);
      float s = 0.f;
      #pragma unroll 8
      for (int c4 = 0; c4 < CDIM/4; c4++){
        float4 wv = wp[c4], av = ap[c4];
        s += wv.x*av.x + wv.y*av.y + wv.z*av.z + wv.w*av.w;
      }
      wd_[gg] = s;
    } else if (g < 2112) {
      int gg = g - 2048; int d = gg >> 2, h = gg & 3;
      const float4* wp = (const float4*)(W_edge + d*HC + h*CDIM);
      const float4* ap = (const float4*)(att_edge + h*CDIM);
      float s = 0.f;
      #pragma unroll 8
      for (int c4 = 0; c4 < CDIM/4; c4++){
        float4 wv = wp[c4], av = ap[c4];
        s += wv.x*av.x + wv.y*av.y + wv.z*av.z + wv.w*av.w;
      }
      we_[gg] = s;
    } else if (g < 2112 + NOUT) {
      counts[g - 2112] = 0;
    }
  } else {
    // edge_attr partial column sums; col-group = idx & 3 (invariant under stride)
    int pb = b - 11;
    const float4* p = (const float4*)ea;
    const int total = NEDGES * 4;           // float4 count
    float4 acc = make_float4(0.f, 0.f, 0.f, 0.f);
    for (int i = pb*256 + tid; i < total; i += MPART*256){
      float4 v = p[i];
      acc.x += v.x; acc.y += v.y; acc.z += v.z; acc.w += v.w;
    }
    // reduce across the 16 lanes sharing lane&3
    #pragma unroll
    for (int off = 4; off <= 32; off <<= 1){
      acc.x += __shfl_xor(acc.x, off, 64);
      acc.y += __shfl_xor(acc.y, off, 64);
      acc.z += __shfl_xor(acc.z, off, 64);
      acc.w += __shfl_xor(acc.w, off, 64);
    }
    __shared__ float4 sd4[16];
    int lane = tid & 63, wave = tid >> 6;
    if (lane < 4) sd4[wave*4 + lane] = acc;
    __syncthreads();
    if (tid < 4){
      float4 t = sd4[tid];
      float4 a = sd4[4+tid], c = sd4[8+tid], d = sd4[12+tid];
      t.x += a.x + c.x + d.x; t.y += a.y + c.y + d.y;
      t.z += a.z + c.z + d.z; t.w += a.w + c.w + d.w;
      easum_part[pb*4 + tid] = t;
    }
  }
}

// K_B: blocks 0..1727 bin edges whose dst is diagonal; block 1728 reduces easum.
__global__ __launch_bounds__(256) void k_scan(const int* __restrict__ ei,
    const float* __restrict__ ea, const float* __restrict__ we_,
    int* __restrict__ counts, int* __restrict__ slist, float* __restrict__ aed,
    const float* __restrict__ easum_part, float* __restrict__ easum){
  int tid = threadIdx.x;
  if (blockIdx.x == NEDGES/256){
    // reduce 512 partial blocks x 16 cols -> easum[16]
    int col = tid & 15, part = tid >> 4;          // 16 parts x 32 pblocks
    float s = 0.f;
    for (int pb = 0; pb < MPART/16; pb++)
      s += easum_part[(part*(MPART/16) + pb)*16 + col];
    __shared__ float sd[256];
    sd[tid] = s;
    __syncthreads();
    if (tid < 16){
      float t = 0.f;
      #pragma unroll
      for (int i = 0; i < 16; i++) t += sd[i*16 + tid];
      easum[tid] = t;
    }
    return;
  }
  int e = blockIdx.x*256 + tid;
  int dst = ei[NEDGES + e];
  int r = dst % N2;
  if (r % 49) return;
  int row = (dst / N2) * NAG + r / 49;
  int pos = atomicAdd(&counts[row], 1);
  if (pos >= CAP) return;
  slist[row*CAP + pos] = ei[e];
  const float* eap = ea + (size_t)e*EDIM;
  float a0=0.f,a1=0.f,a2=0.f,a3=0.f;
  #pragma unroll
  for (int d = 0; d < EDIM; d++){
    float v = eap[d];
    a0 += v*we_[d*4+0]; a1 += v*we_[d*4+1]; a2 += v*we_[d*4+2]; a3 += v*we_[d*4+3];
  }
  float* ap = aed + (size_t)(row*CAP+pos)*4;
  ap[0]=a0; ap[1]=a1; ap[2]=a2; ap[3]=a3;
}

// K_C (mega, 2 rows/block): waves 0-3 -> row A, waves 4-7 -> row B for the
// attention phases; gemm phases share each weight load across both rows and
// split the reduction 4-way (gemm1) / 8-way (gemm2) over the 8 waves.
__global__ __launch_bounds__(512) void k_mega(const float* __restrict__ x,
    const float* __restrict__ ws_, const float* __restrict__ wd_,
    const float* __restrict__ we_, const float* __restrict__ easum,
    const int* __restrict__ counts, const int* __restrict__ slist,
    const float* __restrict__ aed,
    const float* __restrict__ W, const float* __restrict__ bias,
    const float* __restrict__ fcW, const float* __restrict__ fcb,
    float* __restrict__ out){
  __shared__ float  lg[2][(CAP+1)*4];   // 4.1 KB logits/alpha per row
  __shared__ int    srcs[2][CAP+1];     // 1 KB  (srcs[r][k]=dst self-loop)
  __shared__ float  adst[2][4];
  __shared__ float4 zs4[2][256];        // 8 KB combined z per row [h*64+f4]
  __shared__ float  hsf[2][512];        // 4 KB gat row (post-lrelu)
  __shared__ float4 scratch[2048];      // 32 KB phase-aliased partials
  int rowA = blockIdx.x * 2;
  int tid = threadIdx.x;
  int lane = tid & 63, wave = tid >> 6;
  int rsel = wave >> 2;                 // attention row of this wave
  int w4 = wave & 3;                    // wave index within the row

  int kA = counts[rowA];     if (kA > CAP) kA = CAP;
  int kB = counts[rowA + 1]; if (kB > CAP) kB = CAP;
  int myRow = rowA + rsel;
  int myK = rsel ? kB : kA;
  int gg = myRow / NAG, jj = myRow - gg*NAG;
  int myDst = gg*N2 + jj*49;

  // per-lane slice of ws (f = lane*4+q, all 4 heads)
  float wsr[4][4];
  #pragma unroll
  for (int q = 0; q < 4; q++){
    float4 t = *(const float4*)(ws_ + (lane*4+q)*4);
    wsr[q][0]=t.x; wsr[q][1]=t.y; wsr[q][2]=t.z; wsr[q][3]=t.w;
  }

  // edge logits: 4 waves round-robin per row
  for (int i = w4; i < myK; i += 4){
    int src = slist[myRow*CAP + i];
    float4 aedv = *(const float4*)(aed + (size_t)(myRow*CAP+i)*4);
    float4 xv = *(const float4*)(x + (size_t)src*FIN + lane*4);
    float p0 = xv.x*wsr[0][0] + xv.y*wsr[1][0] + xv.z*wsr[2][0] + xv.w*wsr[3][0];
    float p1 = xv.x*wsr[0][1] + xv.y*wsr[1][1] + xv.z*wsr[2][1] + xv.w*wsr[3][1];
    float p2 = xv.x*wsr[0][2] + xv.y*wsr[1][2] + xv.z*wsr[2][2] + xv.w*wsr[3][2];
    float p3 = xv.x*wsr[0][3] + xv.y*wsr[1][3] + xv.z*wsr[2][3] + xv.w*wsr[3][3];
    p0 = wsum(p0); p1 = wsum(p1); p2 = wsum(p2); p3 = wsum(p3);
    if (lane == 0){
      srcs[rsel][i] = src;
      lg[rsel][i*4+0] = p0 + aedv.x; lg[rsel][i*4+1] = p1 + aedv.y;
      lg[rsel][i*4+2] = p2 + aedv.z; lg[rsel][i*4+3] = p3 + aedv.w;
    }
  }

  // waves 0 and 4: a_dst + self-loop logit for their row
  if (w4 == 0){
    float wdr[4][4];
    #pragma unroll
    for (int q = 0; q < 4; q++){
      float4 t = *(const float4*)(wd_ + (lane*4+q)*4);
      wdr[q][0]=t.x; wdr[q][1]=t.y; wdr[q][2]=t.z; wdr[q][3]=t.w;
    }
    float4 xv = *(const float4*)(x + (size_t)myDst*FIN + lane*4);
    float pd[4], ps[4];
    #pragma unroll
    for (int h = 0; h < 4; h++){
      pd[h] = xv.x*wdr[0][h] + xv.y*wdr[1][h] + xv.z*wdr[2][h] + xv.w*wdr[3][h];
      ps[h] = xv.x*wsr[0][h] + xv.y*wsr[1][h] + xv.z*wsr[2][h] + xv.w*wsr[3][h];
    }
    const float invE = 1.0f/(float)NEDGES;
    float md = (lane < 16) ? easum[lane]*invE : 0.f;
    float al[4];
    #pragma unroll
    for (int h = 0; h < 4; h++){
      float c = (lane < 16) ? md*we_[lane*4+h] : 0.f;
      al[h] = wsum(c);
      pd[h] = wsum(pd[h]);
      ps[h] = wsum(ps[h]);
    }
    if (lane == 0){
      #pragma unroll
      for (int h = 0; h < 4; h++){
        adst[rsel][h] = pd[h];
        lg[rsel][myK*4+h] = ps[h] + al[h];
      }
      srcs[rsel][myK] = myDst;   // self-loop src for unified z-accumulation
    }
  }
  __syncthreads();

  // segment softmax: 8 waves = 2 rows x 4 heads
  {
    int r = wave >> 2, h = wave & 3;
    int kk = r ? kB : kA;
    float ad = adst[r][h];
    float m = -1e30f;
    for (int i = lane; i <= kk; i += 64){
      float v = lrelu(lg[r][i*4+h] + ad, 0.2f);
      lg[r][i*4+h] = v;
      m = fmaxf(m, v);
    }
    m = wmax(m);
    float s = 0.f;
    for (int i = lane; i <= kk; i += 64){
      float e = __expf(lg[r][i*4+h] - m);
      lg[r][i*4+h] = e;
      s += e;
    }
    s = wsum(s);
    float inv = 1.0f/(s + 1e-16f);
    for (int i = lane; i <= kk; i += 64) lg[r][i*4+h] *= inv;
  }
  __syncthreads();

  // z accumulation: wave handles its row's edges i = w4, w4+4, ... (incl self)
  {
    float acc[4][4];
    #pragma unroll
    for (int h = 0; h < 4; h++)
      #pragma unroll
      for (int c = 0; c < 4; c++) acc[h][c] = 0.f;
    for (int i = w4; i <= myK; i += 4){
      int src = srcs[rsel][i];
      float4 xv = *(const float4*)(x + (size_t)src*FIN + lane*4);
      float a0 = lg[rsel][i*4+0], a1 = lg[rsel][i*4+1];
      float a2 = lg[rsel][i*4+2], a3 = lg[rsel][i*4+3];
      acc[0][0] += a0*xv.x; acc[0][1] += a0*xv.y; acc[0][2] += a0*xv.z; acc[0][3] += a0*xv.w;
      acc[1][0] += a1*xv.x; acc[1][1] += a1*xv.y; acc[1][2] += a1*xv.z; acc[1][3] += a1*xv.w;
      acc[2][0] += a2*xv.x; acc[2][1] += a2*xv.y; acc[2][2] += a2*xv.z; acc[2][3] += a2*xv.w;
      acc[3][0] += a3*xv.x; acc[3][1] += a3*xv.y; acc[3][2] += a3*xv.z; acc[3][3] += a3*xv.w;
    }
    // scratch as z-partials: [row][w4][h][lane]
    #pragma unroll
    for (int h = 0; h < 4; h++)
      scratch[rsel*1024 + w4*256 + h*64 + lane] =
        make_float4(acc[h][0], acc[h][1], acc[h][2], acc[h][3]);
  }
  __syncthreads();
  {
    // combine 4 wave-partials per row -> zs4
    int r = tid >> 8, s = tid & 255;
    float4 a = scratch[r*1024 + 0*256 + s], b = scratch[r*1024 + 1*256 + s];
    float4 c = scratch[r*1024 + 2*256 + s], d = scratch[r*1024 + 3*256 + s];
    zs4[r][s] = make_float4(a.x+b.x+c.x+d.x, a.y+b.y+c.y+d.y,
                            a.z+b.z+c.z+d.z, a.w+b.w+c.w+d.w);
  }
  __syncthreads();

  // gemm1: thread = (col-group cg 0..127 -> cols 4cg.., quarter q 0..3).
  // Each W float4 load feeds BOTH rows. 64 loads/thread.
  {
    int cg = tid & 127;
    int q  = tid >> 7;
    int h  = cg >> 5;                      // head of this col group
    const float* zA = (const float*)&zs4[0][0] + h*256 + q*64;
    const float* zB = (const float*)&zs4[1][0] + h*256 + q*64;
    const float4* Wp = (const float4*)(W + (size_t)q*64*HC) + cg;
    float4 aA = make_float4(0.f,0.f,0.f,0.f);
    float4 aB = make_float4(0.f,0.f,0.f,0.f);
    #pragma unroll 8
    for (int r = 0; r < 64; r++){
      float4 w4v = Wp[(size_t)r*(HC/4)];
      float za = zA[r], zb = zB[r];
      aA.x += za*w4v.x; aA.y += za*w4v.y; aA.z += za*w4v.z; aA.w += za*w4v.w;
      aB.x += zb*w4v.x; aB.y += zb*w4v.y; aB.z += zb*w4v.z; aB.w += zb*w4v.w;
    }
    scratch[0*512 + q*128 + cg] = aA;
    scratch[1*512 + q*128 + cg] = aB;
  }
  __syncthreads();
  if (tid < 256){
    int r = tid >> 7, cg = tid & 127;
    float4 a = scratch[r*512 + 0*128 + cg], b = scratch[r*512 + 1*128 + cg];
    float4 c = scratch[r*512 + 2*128 + cg], d = scratch[r*512 + 3*128 + cg];
    float4 bs = ((const float4*)bias)[cg];
    hsf[r][4*cg+0] = lrelu(a.x+b.x+c.x+d.x+bs.x, 0.01f);
    hsf[r][4*cg+1] = lrelu(a.y+b.y+c.y+d.y+bs.y, 0.01f);
    hsf[r][4*cg+2] = lrelu(a.z+b.z+c.z+d.z+bs.z, 0.01f);
    hsf[r][4*cg+3] = lrelu(a.w+b.w+c.w+d.w+bs.w, 0.01f);
  }
  __syncthreads();

  // gemm2: thread = (col-group cg 0..63 -> cols 4cg.., eighth e 0..7).
  // Each fcW float4 load feeds BOTH rows. 64 loads/thread.
  {
    int cg = tid & 63;
    int e  = tid >> 6;
    const float4* Fp = (const float4*)(fcW + (size_t)e*64*256) + cg;
    const float* hA = &hsf[0][0] + e*64;
    const float* hB = &hsf[1][0] + e*64;
    float4 aA = make_float4(0.f,0.f,0.f,0.f);
    float4 aB = make_float4(0.f,0.f,0.f,0.f);
    #pragma unroll 8
    for (int r = 0; r < 64; r++){
      float4 w4v = Fp[(size_t)r*64];
      float ha = hA[r], hb = hB[r];
      aA.x += ha*w4v.x; aA.y += ha*w4v.y; aA.z += ha*w4v.z; aA.w += ha*w4v.w;
      aB.x += hb*w4v.x; aB.y += hb*w4v.y; aB.z += hb*w4v.z; aB.w += hb*w4v.w;
    }
    scratch[0*512 + e*64 + cg] = aA;
    scratch[1*512 + e*64 + cg] = aB;
  }
  __syncthreads();
  if (tid < 128){
    int r = tid >> 6, cg = tid & 63;
    float4 s0 = scratch[r*512 + 0*64 + cg];
    #pragma unroll
    for (int e = 1; e < 8; e++){
      float4 t = scratch[r*512 + e*64 + cg];
      s0.x += t.x; s0.y += t.y; s0.z += t.z; s0.w += t.w;
    }
    float4 bs = ((const float4*)fcb)[cg];
    float4 o;
    o.x = lrelu(s0.x+bs.x, 0.01f);
    o.y = lrelu(s0.y+bs.y, 0.01f);
    o.z = lrelu(s0.z+bs.z, 0.01f);
    o.w = lrelu(s0.w+bs.w, 0.01f);
    *(float4*)(out + (size_t)(rowA + r)*256 + 4*cg) = o;
  }
}

extern "C" void kernel_launch(void* const* d_in, const int* in_sizes, int n_in,
                              void* d_out, int out_size, void* d_ws, size_t ws_size,
                              hipStream_t stream) {
  const float* x        = (const float*)d_in[0];
  const int*   ei       = (const int*)  d_in[1];
  const float* ea       = (const float*)d_in[2];
  // d_in[3]=num_groups, d_in[4]=agents_per_group (fixed: 12, 48)
  const float* W        = (const float*)d_in[5];
  const float* att_src  = (const float*)d_in[6];
  const float* att_dst  = (const float*)d_in[7];
  const float* W_edge   = (const float*)d_in[8];
  const float* att_edge = (const float*)d_in[9];
  const float* bias     = (const float*)d_in[10];
  const float* fcW      = (const float*)d_in[11];
  const float* fcb      = (const float*)d_in[12];
  float* out = (float*)d_out;

  float* w = (float*)d_ws;
  float*  ws_       = w;                    // 1024
  float*  wd_       = w + 1024;             // 1024
  float*  we_       = w + 2048;             // 64
  float*  easum     = w + 2112;             // 16
  int*    counts    = (int*)(w + 2128);     // 576
  float*  easum_p   = w + 2704;             // 512*16 = 8192 (16B-aligned)
  int*    slist     = (int*)(w + 10896);    // 576*128 = 73728
  float*  aed       = w + 84624;            // 576*128*4 = 294912 (16B-aligned)

  k_pre<<<11 + MPART, 256, 0, stream>>>(W, att_src, att_dst, W_edge, att_edge, ea,
                                        ws_, wd_, we_, counts, (float4*)easum_p);
  k_scan<<<NEDGES/256 + 1, 256, 0, stream>>>(ei, ea, we_, counts, slist, aed,
                                             easum_p, easum);
  k_mega<<<NOUT/2, 512, 0, stream>>>(x, ws_, wd_, we_, easum, counts, slist, aed,
                                     W, bias, fcW, fcb, out);
}